// Round 27
// baseline (71.407 us; speedup 1.0000x reference)
//
#include <hip/hip_runtime.h>
#include <math.h>

// Problem constants
#define QDIM 512     // 2^9 state dim
#define DD   128     // K*C_IN = input dim of quadratic form
#define LIN  4096
#define LOUT 4089    // (4096 - 7 - 1)/1 + 1
#define NC   16      // C_IN
#define NB   16      // batch

typedef __attribute__((ext_vector_type(8))) short bf16x8;
typedef __attribute__((ext_vector_type(4))) float f32x4;

// Scratch in device globals (NOT d_ws) — R5 lesson. Every element rewritten
// each call before read. R8+R11: no grid barriers. R19: Q-path. R18:
// cooperative LDS staging. R23/R24/R25: latency-bound small kernels ->
// split-K TLP. R26: quadQ m=2 B-frag reuse. R27: mm 2-rows/block at
// PRESERVED 4 waves/SIMD (R23 failed at 1 wave/SIMD; TLP is the constraint,
// bytes the cost) -> W L2 traffic halved.
__device__ float  g_B[QDIM * DD];          // W1 / A (ping-pong) f32
__device__ float  g_C[QDIM * DD];          // W2 f32
__device__ unsigned short g_Qh[DD * DD];   // bf16 hi part of Q
__device__ unsigned short g_Ql[DD * DD];   // bf16 residual of Q

// ---- bf16 helpers (RNE) ----
__device__ __forceinline__ unsigned short f2bf(float f) {
  union { float f; unsigned u; } v; v.f = f;
  unsigned u = v.u + 0x7FFFu + ((v.u >> 16) & 1u);
  return (unsigned short)(u >> 16);
}
__device__ __forceinline__ float bf2f(unsigned short h) {
  union { unsigned u; float f; } v; v.u = ((unsigned)h) << 16;
  return v.f;
}

// ---------------------------------------------------------------------------
// Precompute. Row i of E*R*W = (R^T e_i)^T W (transposed butterflies,
// reverse qubit order, on the E-row in LDS).
// ---------------------------------------------------------------------------
__device__ __forceinline__ void butterfly_T(float* col, const float* theta,
                                            int l, int p) {
  #pragma unroll
  for (int qq = 0; qq < 9; ++qq) {
    int q = 8 - qq;                    // reverse order for transpose
    float half = theta[l * 9 + q] * 0.5f;
    float c = cosf(half), s = sinf(half);
    int right = QDIM >> (q + 1);
    int a = p >> (8 - q);
    int r = p & (right - 1);
    int i0 = (a * 2) * right + r;
    int i1 = i0 + right;
    float v0 = col[i0], v1 = col[i1];
    col[i0] = c * v0 + s * v1;         // transposed 2x2
    col[i1] = c * v1 - s * v0;
    __syncthreads();
  }
}

// W1[i][j] = (R1^T e_i)[j], j<128  -> g_B   (verbatim R20/R26)
__global__ __launch_bounds__(256) void w1_kernel(const float* __restrict__ E,
                                                 const float* __restrict__ theta) {
  __shared__ float erow[QDIM];
  int i = blockIdx.x;
  int p = threadIdx.x;
  erow[p]       = E[i * QDIM + p];
  erow[p + 256] = E[i * QDIM + p + 256];
  __syncthreads();
  butterfly_T(erow, theta, 0, p);
  if (p < DD) g_B[i * DD + p] = erow[p];
}

// dst rows {2i,2i+1} = (R_l^T e_row)^T * src.  256 blocks x 1024 threads:
// 1 block/CU x 16 waves = 4 waves/SIMD (R24's proven TLP) with W read once
// per block (64MB L2/mm, half of R24's 128MB). Per-row chain/reduction
// structure identical to R24 -> absmax canary 4.882812e-4.
__global__ __launch_bounds__(1024) void mm_fused8_kernel(const float* __restrict__ E,
                                                         const float* __restrict__ theta,
                                                         int l, int sel) {
  const float* W = sel ? g_C : g_B;
  float* D       = sel ? g_B : g_C;
  __shared__ float er[2][QDIM];
  __shared__ float part[8][DD];
  int i0 = blockIdx.x * 2;
  int tid = threadIdx.x;                 // 0..1023
  {
    int r = tid >> 9, e = tid & 511;     // two E rows, coalesced
    er[r][e] = E[(size_t)(i0 + r) * QDIM + e];
  }
  __syncthreads();
  // transposed butterflies: 512 workers (256 pairs x 2 rows), barriers outside
  #pragma unroll
  for (int qq = 0; qq < 9; ++qq) {
    int q = 8 - qq;
    float half = theta[l * 9 + q] * 0.5f;
    float c = cosf(half), s = sinf(half);
    if (tid < 512) {
      int rr = tid >> 8;                 // row 0/1
      int p = tid & 255;
      int right = QDIM >> (q + 1);
      int a = p >> (8 - q);
      int r2 = p & (right - 1);
      int x0 = (a * 2) * right + r2;
      int x1 = x0 + right;
      float v0 = er[rr][x0], v1 = er[rr][x1];
      er[rr][x0] = c * v0 + s * v1;
      er[rr][x1] = c * v1 - s * v0;
    }
    __syncthreads();
  }

  int j = tid & 127;
  int grp = tid >> 7;                    // 0..7 = (row<<2) | quarter
  int rr = grp >> 2;
  int qtr = grp & 3;
  float a0 = 0.f, a1 = 0.f, a2 = 0.f, a3 = 0.f;
  int m0 = qtr * 128;
  #pragma unroll 8
  for (int m = m0; m < m0 + 128; m += 4) {
    a0 = fmaf(er[rr][m + 0], W[(m + 0) * DD + j], a0);
    a1 = fmaf(er[rr][m + 1], W[(m + 1) * DD + j], a1);
    a2 = fmaf(er[rr][m + 2], W[(m + 2) * DD + j], a2);
    a3 = fmaf(er[rr][m + 3], W[(m + 3) * DD + j], a3);
  }
  part[grp][j] = (a0 + a1) + (a2 + a3);
  __syncthreads();
  if (tid < 256) {
    int r3 = tid >> 7, jj = tid & 127;
    D[(size_t)(i0 + r3) * DD + jj] =
        (part[r3 * 4 + 0][jj] + part[r3 * 4 + 1][jj]) +
        (part[r3 * 4 + 2][jj] + part[r3 * 4 + 3][jj]);
  }
}

// Q[j1][j2] = sum_i sgn(i) A[i][j1] A[i][j2]; A = g_B. Emit bf16 hi/lo.
// (verbatim R25/R26: 512 threads, split-K x4)
__global__ __launch_bounds__(512) void formq_kernel() {
  const float* A = g_B;
  __shared__ float colA[QDIM];
  __shared__ float part[4][DD];
  int j1 = blockIdx.x;
  int tid = threadIdx.x;                 // 0..511
  int j2 = tid & 127, qtr = tid >> 7;    // 128 j2 x 4 i-quarters
  {
    float sgn = (tid < 256) ? 1.0f : -1.0f;
    colA[tid] = sgn * A[tid * DD + j1];
  }
  __syncthreads();
  float a0 = 0.f, a1 = 0.f, a2 = 0.f, a3 = 0.f;
  int i0 = qtr * 128;
  #pragma unroll 8
  for (int i = i0; i < i0 + 128; i += 4) {
    a0 = fmaf(colA[i + 0], A[(i + 0) * DD + j2], a0);
    a1 = fmaf(colA[i + 1], A[(i + 1) * DD + j2], a1);
    a2 = fmaf(colA[i + 2], A[(i + 2) * DD + j2], a2);
    a3 = fmaf(colA[i + 3], A[(i + 3) * DD + j2], a3);
  }
  part[qtr][j2] = (a0 + a1) + (a2 + a3);
  __syncthreads();
  if (tid < DD) {
    float sum = (part[0][tid] + part[1][tid]) +
                (part[2][tid] + part[3][tid]);
    unsigned short hi = f2bf(sum);
    unsigned short lo = f2bf(sum - bf2f(hi));
    g_Qh[j1 * DD + tid] = hi;
    g_Ql[j1 * DD + tid] = lo;
  }
}

// ---------------------------------------------------------------------------
// quadQ v2 (verbatim R26, measured-good): t-tile 128, 512 blocks, 2/CU;
// Qh staged in LDS (32KB, swizzled) shared by 2 m-tiles; Ql streamed.
// ---------------------------------------------------------------------------
__global__ __launch_bounds__(256, 3) void quadQ_kernel(const float* __restrict__ x,
                                                       float* __restrict__ out) {
  __shared__ float xs[NC][136];                // 135 used (128 t + 7 halo)
  __shared__ unsigned short sh_full[DD * DD];  // Qh, 32 KB, swizzled
  int b = blockIdx.x;
  int t0 = blockIdx.y * 128;
  int tid = threadIdx.x;
  int lane = tid & 63;
  int w = tid >> 6;                            // wave: t-rows [w*32, w*32+32)
  const float* xb = x + (size_t)b * NC * LIN;

  for (int idx = tid; idx < NC * 135; idx += 256) {
    int c = idx / 135, o = idx % 135;
    int g = t0 + o;
    xs[c][o] = (g < LIN) ? xb[c * LIN + g] : 0.0f;
  }
  // stage Qh (2048 granules of 8 u16), XOR swizzle: u16col ^= (row&7)<<3
  #pragma unroll
  for (int it = 0; it < 8; ++it) {
    int flat = it * 256 + tid;
    int row = flat >> 4;                       // 0..127
    int g8 = flat & 15;
    int lidx = row * DD + ((g8 * 8) ^ ((row & 7) << 3));
    *(bf16x8*)&sh_full[lidx] = *(const bf16x8*)(g_Qh + row * DD + g8 * 8);
  }
  __syncthreads();

  int lrow = lane & 15;
  int lgrp = lane >> 4;

  f32x4 acc[2][8];
  #pragma unroll
  for (int m = 0; m < 2; ++m)
    #pragma unroll
    for (int n = 0; n < 8; ++n) acc[m][n] = (f32x4){0.f, 0.f, 0.f, 0.f};

  #pragma unroll
  for (int kb = 0; kb < 4; ++kb) {
    int c = kb * 4 + lgrp;
    bf16x8 a_hi[2], a_lo[2];
    #pragma unroll
    for (int m = 0; m < 2; ++m) {
      int tl = w * 32 + m * 16 + lrow;
      #pragma unroll
      for (int e = 0; e < 8; ++e) {
        float v = xs[c][tl + e];
        unsigned short hh = f2bf(v);
        unsigned short ll = f2bf(v - bf2f(hh));
        a_hi[m][e] = (short)hh;
        a_lo[m][e] = (short)ll;
      }
    }
    #pragma unroll
    for (int n = 0; n < 8; ++n) {
      int row = n * 16 + lrow;
      int col = kb * 32 + lgrp * 8;
      bf16x8 b_hi = *(const bf16x8*)&sh_full[row * DD + (col ^ ((row & 7) << 3))];
      bf16x8 b_lo = *(const bf16x8*)(g_Ql + row * DD + col);
      #pragma unroll
      for (int m = 0; m < 2; ++m) {
        acc[m][n] = __builtin_amdgcn_mfma_f32_16x16x32_bf16(a_hi[m], b_hi, acc[m][n], 0, 0, 0);
        acc[m][n] = __builtin_amdgcn_mfma_f32_16x16x32_bf16(a_hi[m], b_lo, acc[m][n], 0, 0, 0);
        acc[m][n] = __builtin_amdgcn_mfma_f32_16x16x32_bf16(a_lo[m], b_hi, acc[m][n], 0, 0, 0);
      }
    }
  }

  // Epilogue: dot with v and ||v||^2, 16-lane reduce (per m-tile).
  float pd[2][4] = {{0.f,0.f,0.f,0.f},{0.f,0.f,0.f,0.f}};
  float pn[2][4] = {{0.f,0.f,0.f,0.f},{0.f,0.f,0.f,0.f}};
  #pragma unroll
  for (int n = 0; n < 8; ++n) {
    int i = n * 16 + lrow;
    int cc = i >> 3, ko = i & 7;
    #pragma unroll
    for (int m = 0; m < 2; ++m) {
      #pragma unroll
      for (int r = 0; r < 4; ++r) {
        int tl = w * 32 + m * 16 + lgrp * 4 + r;
        float v = xs[cc][tl + ko];
        pd[m][r] = fmaf(acc[m][n][r], v, pd[m][r]);
        pn[m][r] = fmaf(v, v, pn[m][r]);
      }
    }
  }
  #pragma unroll
  for (int m = 0; m < 2; ++m)
    #pragma unroll
    for (int r = 0; r < 4; ++r) {
      #pragma unroll
      for (int msk = 1; msk < 16; msk <<= 1) {
        pd[m][r] += __shfl_xor(pd[m][r], msk);
        pn[m][r] += __shfl_xor(pn[m][r], msk);
      }
    }
  if (lrow == 0) {
    #pragma unroll
    for (int m = 0; m < 2; ++m)
      #pragma unroll
      for (int r = 0; r < 4; ++r) {
        int t = t0 + w * 32 + m * 16 + lgrp * 4 + r;
        if (t < LOUT) out[(size_t)b * LOUT + t] = pd[m][r] / (pn[m][r] + 1e-12f);
      }
  }
}

// ---------------------------------------------------------------------------

extern "C" void kernel_launch(void* const* d_in, const int* in_sizes, int n_in,
                              void* d_out, int out_size, void* d_ws, size_t ws_size,
                              hipStream_t stream) {
  const float* x     = (const float*)d_in[0];   // (16,16,4096) f32
  const float* E     = (const float*)d_in[1];   // (512,512)    f32
  const float* theta = (const float*)d_in[2];   // (3,9)        f32
  float* out = (float*)d_out;                   // (16,1,1,4089) f32
  (void)d_ws; (void)ws_size;

  w1_kernel<<<QDIM, 256, 0, stream>>>(E, theta);                  // -> g_B (W1)
  mm_fused8_kernel<<<QDIM / 2, 1024, 0, stream>>>(E, theta, 1, 0); // g_B -> g_C
  mm_fused8_kernel<<<QDIM / 2, 1024, 0, stream>>>(E, theta, 2, 1); // g_C -> g_B (A)
  formq_kernel<<<DD, 512, 0, stream>>>();                         // g_B -> g_Qh/g_Ql
  quadQ_kernel<<<dim3(NB, 32), 256, 0, stream>>>(x, out);
}

// Round 28
// 47.863 us; speedup vs baseline: 1.4919x; 1.4919x over previous
//
#include <hip/hip_runtime.h>
#include <math.h>

// Problem constants
#define QDIM 512     // 2^9 state dim
#define DD   128     // K*C_IN = input dim of quadratic form
#define LIN  4096
#define LOUT 4089    // (4096 - 7 - 1)/1 + 1
#define NC   16      // C_IN
#define NB   16      // batch

typedef __attribute__((ext_vector_type(8))) short bf16x8;
typedef __attribute__((ext_vector_type(4))) float f32x4;

// Scratch in device globals (NOT d_ws) — R5 lesson. Every element rewritten
// each call before read. R8+R11: no grid barriers. R19: Q-path. R18:
// cooperative LDS staging. R23/R24/R25: latency-bound small kernels ->
// split-K TLP at 512 thr / 512 blocks (R23: fewer blocks regress; R27:
// 1024-thr blocks regress — mm geometry is a confirmed local optimum).
// R26: quadQ m=2 B-frag reuse. This file = R26 verbatim (best: 48.0us).
__device__ float  g_B[QDIM * DD];          // W1 / A (ping-pong) f32
__device__ float  g_C[QDIM * DD];          // W2 f32
__device__ unsigned short g_Qh[DD * DD];   // bf16 hi part of Q
__device__ unsigned short g_Ql[DD * DD];   // bf16 residual of Q

// ---- bf16 helpers (RNE) ----
__device__ __forceinline__ unsigned short f2bf(float f) {
  union { float f; unsigned u; } v; v.f = f;
  unsigned u = v.u + 0x7FFFu + ((v.u >> 16) & 1u);
  return (unsigned short)(u >> 16);
}
__device__ __forceinline__ float bf2f(unsigned short h) {
  union { unsigned u; float f; } v; v.u = ((unsigned)h) << 16;
  return v.f;
}

// ---------------------------------------------------------------------------
// Precompute. Row i of E*R*W = (R^T e_i)^T W (transposed butterflies,
// reverse qubit order, on the E-row in LDS).
// ---------------------------------------------------------------------------
__device__ __forceinline__ void butterfly_T(float* col, const float* theta,
                                            int l, int p) {
  #pragma unroll
  for (int qq = 0; qq < 9; ++qq) {
    int q = 8 - qq;                    // reverse order for transpose
    float half = theta[l * 9 + q] * 0.5f;
    float c = cosf(half), s = sinf(half);
    int right = QDIM >> (q + 1);
    int a = p >> (8 - q);
    int r = p & (right - 1);
    int i0 = (a * 2) * right + r;
    int i1 = i0 + right;
    float v0 = col[i0], v1 = col[i1];
    col[i0] = c * v0 + s * v1;         // transposed 2x2
    col[i1] = c * v1 - s * v0;
    __syncthreads();
  }
}

// W1[i][j] = (R1^T e_i)[j], j<128  -> g_B
__global__ __launch_bounds__(256) void w1_kernel(const float* __restrict__ E,
                                                 const float* __restrict__ theta) {
  __shared__ float erow[QDIM];
  int i = blockIdx.x;
  int p = threadIdx.x;
  erow[p]       = E[i * QDIM + p];
  erow[p + 256] = E[i * QDIM + p + 256];
  __syncthreads();
  butterfly_T(erow, theta, 0, p);
  if (p < DD) g_B[i * DD + p] = erow[p];
}

// dst[i][:] = (R_l^T e_i)^T * src.  512 blocks x 512 threads (4 K-quarters)
// -> 4 waves/SIMD (R24, measured-good; both neighbors in geometry space
// measured worse: R23 256blk/256thr, R27 256blk/1024thr).
__global__ __launch_bounds__(512) void mm_fused4_kernel(const float* __restrict__ E,
                                                        const float* __restrict__ theta,
                                                        int l, int sel) {
  const float* W = sel ? g_C : g_B;
  float* D       = sel ? g_B : g_C;
  __shared__ float erow[QDIM];
  __shared__ float part[4][DD];
  int i = blockIdx.x;
  int tid = threadIdx.x;                 // 0..511
  erow[tid] = E[i * QDIM + tid];
  __syncthreads();
  // transposed butterflies: 256 worker threads, barriers outside the guard
  #pragma unroll
  for (int qq = 0; qq < 9; ++qq) {
    int q = 8 - qq;
    float half = theta[l * 9 + q] * 0.5f;
    float c = cosf(half), s = sinf(half);
    if (tid < 256) {
      int right = QDIM >> (q + 1);
      int a = tid >> (8 - q);
      int r = tid & (right - 1);
      int x0 = (a * 2) * right + r;
      int x1 = x0 + right;
      float v0 = erow[x0], v1 = erow[x1];
      erow[x0] = c * v0 + s * v1;
      erow[x1] = c * v1 - s * v0;
    }
    __syncthreads();
  }

  int j = tid & 127, qtr = tid >> 7;     // 128 j x 4 K-quarters
  float a0 = 0.f, a1 = 0.f, a2 = 0.f, a3 = 0.f;
  int m0 = qtr * 128;
  #pragma unroll 8
  for (int m = m0; m < m0 + 128; m += 4) {
    a0 = fmaf(erow[m + 0], W[(m + 0) * DD + j], a0);
    a1 = fmaf(erow[m + 1], W[(m + 1) * DD + j], a1);
    a2 = fmaf(erow[m + 2], W[(m + 2) * DD + j], a2);
    a3 = fmaf(erow[m + 3], W[(m + 3) * DD + j], a3);
  }
  part[qtr][j] = (a0 + a1) + (a2 + a3);
  __syncthreads();
  if (tid < DD) {
    D[i * DD + tid] = (part[0][tid] + part[1][tid]) +
                      (part[2][tid] + part[3][tid]);
  }
}

// Q[j1][j2] = sum_i sgn(i) A[i][j1] A[i][j2]; A = g_B. Emit bf16 hi/lo.
// (R25: 512 threads, split-K x4)
__global__ __launch_bounds__(512) void formq_kernel() {
  const float* A = g_B;
  __shared__ float colA[QDIM];
  __shared__ float part[4][DD];
  int j1 = blockIdx.x;
  int tid = threadIdx.x;                 // 0..511
  int j2 = tid & 127, qtr = tid >> 7;    // 128 j2 x 4 i-quarters
  {
    float sgn = (tid < 256) ? 1.0f : -1.0f;
    colA[tid] = sgn * A[tid * DD + j1];
  }
  __syncthreads();
  float a0 = 0.f, a1 = 0.f, a2 = 0.f, a3 = 0.f;
  int i0 = qtr * 128;
  #pragma unroll 8
  for (int i = i0; i < i0 + 128; i += 4) {
    a0 = fmaf(colA[i + 0], A[(i + 0) * DD + j2], a0);
    a1 = fmaf(colA[i + 1], A[(i + 1) * DD + j2], a1);
    a2 = fmaf(colA[i + 2], A[(i + 2) * DD + j2], a2);
    a3 = fmaf(colA[i + 3], A[(i + 3) * DD + j2], a3);
  }
  part[qtr][j2] = (a0 + a1) + (a2 + a3);
  __syncthreads();
  if (tid < DD) {
    float sum = (part[0][tid] + part[1][tid]) +
                (part[2][tid] + part[3][tid]);
    unsigned short hi = f2bf(sum);
    unsigned short lo = f2bf(sum - bf2f(hi));
    g_Qh[j1 * DD + tid] = hi;
    g_Ql[j1 * DD + tid] = lo;
  }
}

// ---------------------------------------------------------------------------
// quadQ v2 (R26, measured-good): t-tile 128, 512 blocks, 2/CU; Qh staged
// in LDS (32KB, swizzled) shared by 2 m-tiles; Ql streamed from L2.
// ---------------------------------------------------------------------------
__global__ __launch_bounds__(256, 3) void quadQ_kernel(const float* __restrict__ x,
                                                       float* __restrict__ out) {
  __shared__ float xs[NC][136];                // 135 used (128 t + 7 halo)
  __shared__ unsigned short sh_full[DD * DD];  // Qh, 32 KB, swizzled
  int b = blockIdx.x;
  int t0 = blockIdx.y * 128;
  int tid = threadIdx.x;
  int lane = tid & 63;
  int w = tid >> 6;                            // wave: t-rows [w*32, w*32+32)
  const float* xb = x + (size_t)b * NC * LIN;

  for (int idx = tid; idx < NC * 135; idx += 256) {
    int c = idx / 135, o = idx % 135;
    int g = t0 + o;
    xs[c][o] = (g < LIN) ? xb[c * LIN + g] : 0.0f;
  }
  // stage Qh (2048 granules of 8 u16), XOR swizzle: u16col ^= (row&7)<<3
  #pragma unroll
  for (int it = 0; it < 8; ++it) {
    int flat = it * 256 + tid;
    int row = flat >> 4;                       // 0..127
    int g8 = flat & 15;
    int lidx = row * DD + ((g8 * 8) ^ ((row & 7) << 3));
    *(bf16x8*)&sh_full[lidx] = *(const bf16x8*)(g_Qh + row * DD + g8 * 8);
  }
  __syncthreads();

  int lrow = lane & 15;
  int lgrp = lane >> 4;

  f32x4 acc[2][8];
  #pragma unroll
  for (int m = 0; m < 2; ++m)
    #pragma unroll
    for (int n = 0; n < 8; ++n) acc[m][n] = (f32x4){0.f, 0.f, 0.f, 0.f};

  #pragma unroll
  for (int kb = 0; kb < 4; ++kb) {
    int c = kb * 4 + lgrp;
    bf16x8 a_hi[2], a_lo[2];
    #pragma unroll
    for (int m = 0; m < 2; ++m) {
      int tl = w * 32 + m * 16 + lrow;
      #pragma unroll
      for (int e = 0; e < 8; ++e) {
        float v = xs[c][tl + e];
        unsigned short hh = f2bf(v);
        unsigned short ll = f2bf(v - bf2f(hh));
        a_hi[m][e] = (short)hh;
        a_lo[m][e] = (short)ll;
      }
    }
    #pragma unroll
    for (int n = 0; n < 8; ++n) {
      int row = n * 16 + lrow;
      int col = kb * 32 + lgrp * 8;
      bf16x8 b_hi = *(const bf16x8*)&sh_full[row * DD + (col ^ ((row & 7) << 3))];
      bf16x8 b_lo = *(const bf16x8*)(g_Ql + row * DD + col);
      #pragma unroll
      for (int m = 0; m < 2; ++m) {
        acc[m][n] = __builtin_amdgcn_mfma_f32_16x16x32_bf16(a_hi[m], b_hi, acc[m][n], 0, 0, 0);
        acc[m][n] = __builtin_amdgcn_mfma_f32_16x16x32_bf16(a_hi[m], b_lo, acc[m][n], 0, 0, 0);
        acc[m][n] = __builtin_amdgcn_mfma_f32_16x16x32_bf16(a_lo[m], b_hi, acc[m][n], 0, 0, 0);
      }
    }
  }

  // Epilogue: dot with v and ||v||^2, 16-lane reduce (per m-tile).
  float pd[2][4] = {{0.f,0.f,0.f,0.f},{0.f,0.f,0.f,0.f}};
  float pn[2][4] = {{0.f,0.f,0.f,0.f},{0.f,0.f,0.f,0.f}};
  #pragma unroll
  for (int n = 0; n < 8; ++n) {
    int i = n * 16 + lrow;
    int cc = i >> 3, ko = i & 7;
    #pragma unroll
    for (int m = 0; m < 2; ++m) {
      #pragma unroll
      for (int r = 0; r < 4; ++r) {
        int tl = w * 32 + m * 16 + lgrp * 4 + r;
        float v = xs[cc][tl + ko];
        pd[m][r] = fmaf(acc[m][n][r], v, pd[m][r]);
        pn[m][r] = fmaf(v, v, pn[m][r]);
      }
    }
  }
  #pragma unroll
  for (int m = 0; m < 2; ++m)
    #pragma unroll
    for (int r = 0; r < 4; ++r) {
      #pragma unroll
      for (int msk = 1; msk < 16; msk <<= 1) {
        pd[m][r] += __shfl_xor(pd[m][r], msk);
        pn[m][r] += __shfl_xor(pn[m][r], msk);
      }
    }
  if (lrow == 0) {
    #pragma unroll
    for (int m = 0; m < 2; ++m)
      #pragma unroll
      for (int r = 0; r < 4; ++r) {
        int t = t0 + w * 32 + m * 16 + lgrp * 4 + r;
        if (t < LOUT) out[(size_t)b * LOUT + t] = pd[m][r] / (pn[m][r] + 1e-12f);
      }
  }
}

// ---------------------------------------------------------------------------

extern "C" void kernel_launch(void* const* d_in, const int* in_sizes, int n_in,
                              void* d_out, int out_size, void* d_ws, size_t ws_size,
                              hipStream_t stream) {
  const float* x     = (const float*)d_in[0];   // (16,16,4096) f32
  const float* E     = (const float*)d_in[1];   // (512,512)    f32
  const float* theta = (const float*)d_in[2];   // (3,9)        f32
  float* out = (float*)d_out;                   // (16,1,1,4089) f32
  (void)d_ws; (void)ws_size;

  w1_kernel<<<QDIM, 256, 0, stream>>>(E, theta);                 // -> g_B (W1)
  mm_fused4_kernel<<<QDIM, 512, 0, stream>>>(E, theta, 1, 0);    // g_B -> g_C
  mm_fused4_kernel<<<QDIM, 512, 0, stream>>>(E, theta, 2, 1);    // g_C -> g_B (A)
  formq_kernel<<<DD, 512, 0, stream>>>();                        // g_B -> g_Qh/g_Ql
  quadQ_kernel<<<dim3(NB, 32), 256, 0, stream>>>(x, out);
}